// Round 8
// baseline (276.619 us; speedup 1.0000x reference)
//
#include <hip/hip_runtime.h>
#include <math.h>

#define NANCH 76725
#define NCLS 80
#define NIMG 4
#define PREK 512
#define MAXDET 100
#define CONF_THRF 0.05f
#define IOU_THRF 0.5f
#define XCUT 2.2f            // logit cut: sigmoid(2.2)=0.90025; 512th-best per class ~0.92
#define NSTRIPE 16           // per-class atomic striping (by blockIdx.x & 15)
#define SCAP 128             // capacity per (class,stripe) sub-list; expected ~67 +/- 8
#define F4_PER_IMG 1611225   // 76725*84/4
#define EL_PER_IMG 6444900   // 76725*84
#define NSUB (NIMG * NCLS * NSTRIPE)   // 5120 sub-lists
#define NBC (NIMG * NCLS)              // 320 (image,class) pairs

__device__ __forceinline__ unsigned mono_key(float s) {
    unsigned b = __float_as_uint(s);
    return (b & 0x80000000u) ? ~b : (b | 0x80000000u);
}
__device__ __forceinline__ float mono_val(unsigned k) {
    return (k & 0x80000000u) ? __uint_as_float(k ^ 0x80000000u) : __uint_as_float(~k);
}
// Correctly-rounded-to-f32 sigmoid via double; matched XLA exactly (absmax 0.0 r1-r7).
__device__ __forceinline__ float sigmoid_f(float x) {
    return (float)(1.0 / (1.0 + exp(-(double)x)));
}

__device__ __forceinline__ unsigned long long shflx64(unsigned long long v, int d) {
    unsigned lo = (unsigned)v, hi = (unsigned)(v >> 32);
    lo = (unsigned)__shfl_xor((int)lo, d, 64);
    hi = (unsigned)__shfl_xor((int)hi, d, 64);
    return ((unsigned long long)hi << 32) | (unsigned long long)lo;
}
__device__ __forceinline__ unsigned long long ce_dir(unsigned long long v, unsigned long long u,
                                                     unsigned idx, unsigned j, unsigned k) {
    bool take_max = (((idx & k) == 0u) == ((idx & j) == 0u));
    bool u_gt = (u > v);
    return (take_max == u_gt) ? u : v;
}

// RetinaNet anchors, levels 3..7, 640x640, xywh. Replicates reference float32 math.
__device__ void anchor_at(int idx, float& ax, float& ay, float& aw, float& ah) {
    int l, li = idx;
    if (idx < 57600)      { l = 0; }
    else if (idx < 72000) { l = 1; li = idx - 57600; }
    else if (idx < 75600) { l = 2; li = idx - 72000; }
    else if (idx < 76500) { l = 3; li = idx - 75600; }
    else                  { l = 4; li = idx - 76500; }
    int stride = 8 << l;
    int fsz = 640 >> (3 + l);
    int cell = li / 9, a = li - cell * 9;
    int cyi = cell / fsz, cxi = cell - cyi * fsz;
    float fst = (float)stride;
    ax = ((float)cxi + 0.5f) * fst;
    ay = ((float)cyi + 0.5f) * fst;
    float side = (float)(stride * 4);
    float area = side * side;
    int ri = a / 3, si = a - ri * 3;
    float ratio = (ri == 0) ? 0.5f : ((ri == 1) ? 1.0f : 2.0f);
    float scl = (si == 0) ? 1.0f
              : ((si == 1) ? 1.25992104989487316476721f
                           : 1.58740105196819947475170564f);
    float h = sqrtf(area / ratio);
    float w = area / h;
    aw = scl * w;
    ah = scl * h;
}

// counters padded to one 64B line each: gcnt[sub*16]
__device__ __forceinline__ void emit_one(int b, unsigned el, float x, unsigned stripe,
                                         unsigned long long* glist, unsigned* gcnt) {
    unsigned anchor = el / 84u;
    unsigned col = el - anchor * 84u;
    int c = (int)col - 4;
    unsigned key = mono_key(sigmoid_f(x));
    unsigned sub = (unsigned)(b * NCLS + c) * NSTRIPE + stripe;
    unsigned pos = atomicAdd(&gcnt[sub << 4], 1u);
    if (pos < SCAP)
        glist[(size_t)sub * SCAP + pos] =
            ((unsigned long long)key << 32) | (unsigned long long)(0xFFFFFFFFu - anchor);
}

// ---------------- Kernel 1: threshold-collect (pure-ILP stream + dense tail) --
__global__ __launch_bounds__(256, 4) void collect_kernel(const float* __restrict__ pred,
                                                         unsigned long long* __restrict__ glist,
                                                         unsigned* __restrict__ gcnt) {
    __shared__ unsigned pend[512];
    __shared__ unsigned s_p;
    int b = blockIdx.y;
    int tid = threadIdx.x;
    unsigned stripe = (unsigned)blockIdx.x & (NSTRIPE - 1u);
    if (tid == 0) s_p = 0u;
    __syncthreads();
    const float4* p4 = (const float4*)(pred + (size_t)b * EL_PER_IMG);
    unsigned base4 = (unsigned)blockIdx.x * 2560u + (unsigned)tid;

    float4 v[10];
    unsigned fidx[10];
#pragma unroll
    for (int k = 0; k < 10; k++) {
        unsigned f = base4 + (unsigned)k * 256u;
        fidx[k] = f;
        unsigned fc = (f < (unsigned)F4_PER_IMG) ? f : (unsigned)(F4_PER_IMG - 1);
        v[k] = p4[fc];
    }
#pragma unroll
    for (int k = 0; k < 10; k++) {
        unsigned f = fidx[k];
        bool ok = (f < (unsigned)F4_PER_IMG) && (f % 21u != 0u);  // %21==0 => box cols
        float4 w = v[k];
        if (ok && (w.x >= XCUT || w.y >= XCUT || w.z >= XCUT || w.w >= XCUT)) {
#pragma unroll
            for (int j = 0; j < 4; j++) {
                float x = (j == 0) ? w.x : (j == 1) ? w.y : (j == 2) ? w.z : w.w;
                if (x >= XCUT) {
                    unsigned pos = atomicAdd(&s_p, 1u);
                    unsigned el = f * 4u + (unsigned)j;
                    if (pos < 512u) pend[pos] = el;
                    else emit_one(b, el, x, stripe, glist, gcnt);
                }
            }
        }
    }
    __syncthreads();
    unsigned np = s_p; if (np > 512u) np = 512u;
    for (unsigned i = (unsigned)tid; i < np; i += 256u) {
        unsigned el = pend[i];
        float x = pred[(size_t)b * EL_PER_IMG + el];
        emit_one(b, el, x, stripe, glist, gcnt);
    }
}

// parallel suffix (inclusive, from high index down) over 2048 u32 in LDS, 512 thr
__device__ __forceinline__ void suffix_scan_2048(unsigned* h, int tid) {
    for (unsigned off = 1; off < 2048; off <<= 1) {
        unsigned v[4];
#pragma unroll
        for (int q = 0; q < 4; q++) {
            unsigned t = (unsigned)tid + q * 512u;
            v[q] = (t + off < 2048u) ? h[t + off] : 0u;
        }
        __syncthreads();
#pragma unroll
        for (int q = 0; q < 4; q++) h[tid + q * 512] += v[q];
        __syncthreads();
    }
}

// ---------------- Kernel 2: FUSED select + decode + adaptive NMS + epilogue ---
// LDS overlay: select phase (clist 16K | sout 8K | eqbuf 4K = 28.7K) and NMS
// phase (rowb 34.8K | sbox 8K | sarea 2K | svalid 2K = 47.1K) share one 47104-B
// arena; decoded boxes cross the boundary in registers. 3 blocks/CU -> all 320
// co-resident. The 80th-finishing block per image runs the image-wide top-100
// radix select in-place (last-block-done epilogue, no extra launch).
__global__ __launch_bounds__(512) void select_nms_fused(
        const float* __restrict__ pred, const unsigned long long* __restrict__ glist,
        const unsigned* __restrict__ gcnt,
        float* __restrict__ cls_scores, float* __restrict__ cls_boxes,
        unsigned* __restrict__ done, float* __restrict__ out) {
    int bc = blockIdx.x;
    int b = bc / NCLS, c = bc - b * NCLS;
    int tid = threadIdx.x;

    __shared__ __align__(16) unsigned char smem[47104];
    // select-phase overlay
    unsigned long long* clist = (unsigned long long*)smem;            // 2048 u64
    unsigned long long* sout  = (unsigned long long*)(smem + 16384);  // 1024 u64
    unsigned* eqbuf = (unsigned*)(smem + 24576);                      // 1024 u32
    // NMS-phase overlay
    unsigned* rowb = (unsigned*)smem;                                 // 512*17 u32
    float4* sbox = (float4*)(smem + 34816);                           // 512
    float* sarea = (float*)(smem + 43008);                            // 512
    int* svalid = (int*)(smem + 45056);                               // 512

    __shared__ unsigned scnt[NSTRIPE], soff[NSTRIPE], wsum[8];
    __shared__ int s_ok, s_last;
    __shared__ unsigned s_total, s_tb, a_ctr, e_ctr, s_fail;
    __shared__ unsigned sh_t, sh_above, s_cnt, s_eq;
    __shared__ unsigned keepw[16], svalw[16], s_kept;
    // epilogue statics
    __shared__ unsigned thist[256], wpart[4];
    __shared__ unsigned long long win[128], balw[8];
    __shared__ unsigned s_prefix, s_need, s_bin, s_abv, s_istar, w_ctr;

    unsigned* hist = eqbuf;                      // 512 bins (fast path)

    const unsigned KCUT = mono_key(sigmoid_f(XCUT));
    const unsigned BASE = KCUT >> 12;            // fast keys in (KCUT, mono(1.0f)]

    if (tid < NSTRIPE)
        scnt[tid] = gcnt[(((unsigned)bc * NSTRIPE + (unsigned)tid) << 4)];
    for (int i = tid; i < 1024; i += 512) sout[i] = 0ull;
    if (tid < 512) hist[tid] = 0u;
    if (tid == 0) { a_ctr = 0u; e_ctr = 0u; s_fail = 0u; }
    __syncthreads();
    if (tid == 0) {
        unsigned o = 0; int ok = 1;
        for (int s = 0; s < NSTRIPE; s++) {
            unsigned cs_ = scnt[s];
            if (cs_ > SCAP) ok = 0;
            soff[s] = o;
            o += (cs_ < SCAP ? cs_ : SCAP);
        }
        s_total = o;
        s_ok = ok && (o >= PREK);
    }
    __syncthreads();

    // gather: 4 fully-independent vector loads per thread
#pragma unroll
    for (int q = 0; q < 4; q++) {
        unsigned qq = (unsigned)tid + (unsigned)q * 512u;       // < 2048 = 16*128
        unsigned s = qq >> 7, i = qq & (SCAP - 1u);
        unsigned long long e2 = glist[(size_t)((unsigned)bc * NSTRIPE + s) * SCAP + i];
        unsigned cs_ = scnt[s]; if (cs_ > SCAP) cs_ = SCAP;
        if (i < cs_) {
            clist[soff[s] + i] = e2;
            int bin = (int)((unsigned)(e2 >> 32) >> 12) - (int)BASE;
            bin = bin < 0 ? 0 : (bin > 511 ? 511 : bin);
            atomicAdd(&hist[bin], 1u);
        }
    }
    __syncthreads();

    bool fastb = (s_ok != 0);
    if (fastb) {
        unsigned vbin = hist[tid];
        int lane = tid & 63, w8 = tid >> 6;
#pragma unroll
        for (int off = 1; off < 64; off <<= 1) {
            unsigned u = (unsigned)__shfl_down((int)vbin, off, 64);
            if (lane + off < 64) vbin += u;
        }
        if (lane == 0) wsum[w8] = vbin;
        __syncthreads();
        if (tid == 0) {
            unsigned acc = 0;
            for (int w = 7; w >= 0; w--) { unsigned t = wsum[w]; wsum[w] = acc; acc += t; }
        }
        __syncthreads();
        vbin += wsum[w8];
        hist[tid] = vbin;          // suffix counts
        __syncthreads();
        unsigned S = vbin, S1 = (tid < 511) ? hist[tid + 1] : 0u;
        if (S >= PREK && S1 < PREK) s_tb = (unsigned)tid;
        __syncthreads();
        unsigned tb = s_tb;
        unsigned total = s_total;
        for (unsigned i = (unsigned)tid; i < total; i += 512u) {
            unsigned long long e2 = clist[i];
            int bin = (int)((unsigned)(e2 >> 32) >> 12) - (int)BASE;
            bin = bin < 0 ? 0 : (bin > 511 ? 511 : bin);
            if ((unsigned)bin > tb) {
                unsigned p = atomicAdd(&a_ctr, 1u);
                sout[p] = e2;
            } else if ((unsigned)bin == tb) {
                unsigned p = atomicAdd(&e_ctr, 1u);
                if (p < 512u) sout[512u + p] = e2;
                else s_fail = 1u;
            }
        }
        __syncthreads();
        if (s_fail) fastb = false;
    }
    if (fastb) {
        unsigned i0 = (unsigned)tid * 2u, i1 = i0 + 1u;
        unsigned long long v0 = sout[i0], v1 = sout[i1];
        for (unsigned k = 2; k <= 1024; k <<= 1) {
            for (unsigned j = k >> 1; j >= 1; j >>= 1) {
                if (j >= 128) {
                    sout[i0] = v0; sout[i1] = v1;
                    __syncthreads();
                    unsigned long long u0 = sout[i0 ^ j], u1 = sout[i1 ^ j];
                    v0 = ce_dir(v0, u0, i0, j, k);
                    v1 = ce_dir(v1, u1, i1, j, k);
                    __syncthreads();
                } else if (j >= 2) {
                    int d = (int)(j >> 1);
                    unsigned long long u0 = shflx64(v0, d), u1 = shflx64(v1, d);
                    v0 = ce_dir(v0, u0, i0, j, k);
                    v1 = ce_dir(v1, u1, i1, j, k);
                } else {
                    bool tm = ((i0 & k) == 0u);
                    unsigned long long mx = v0 > v1 ? v0 : v1;
                    unsigned long long mn = v0 > v1 ? v1 : v0;
                    v0 = tm ? mx : mn; v1 = tm ? mn : mx;
                }
            }
        }
        sout[i0] = v0; sout[i1] = v1;
        __syncthreads();
        unsigned key511 = (unsigned)(sout[511] >> 32);
        fastb = key511 > KCUT;     // proof: every uncollected key <= KCUT
    }

    if (!fastb) {
        // exact 3-level radix-select fallback (never taken on bench input)
        unsigned* fhist = (unsigned*)sout;       // 2048 u32
        unsigned* eqlist = eqbuf;                // 1024 u32
        const float* predc = pred + (size_t)b * NANCH * 84 + 4 + c;
        auto getkey = [&](int i) -> unsigned {
            return mono_key(sigmoid_f(predc[(size_t)i * 84]));
        };
        __syncthreads();
        for (int t = tid; t < 2048; t += 512) fhist[t] = 0u;
        __syncthreads();
        for (int i = tid; i < NANCH; i += 512) atomicAdd(&fhist[getkey(i) >> 21], 1u);
        __syncthreads();
        suffix_scan_2048(fhist, tid);
        unsigned target = PREK;
#pragma unroll
        for (int q = 0; q < 4; q++) {
            int t = tid + q * 512;
            unsigned St = fhist[t], St1 = (t < 2047) ? fhist[t + 1] : 0u;
            if (St >= target && St1 < target) { sh_t = (unsigned)t; sh_above = St1; }
        }
        __syncthreads();
        unsigned t0 = sh_t, above = sh_above;
        __syncthreads();
        for (int t = tid; t < 2048; t += 512) fhist[t] = 0u;
        __syncthreads();
        for (int i = tid; i < NANCH; i += 512) {
            unsigned k = getkey(i);
            if ((k >> 21) == t0) atomicAdd(&fhist[(k >> 10) & 0x7FFu], 1u);
        }
        __syncthreads();
        suffix_scan_2048(fhist, tid);
        target = PREK - above;
#pragma unroll
        for (int q = 0; q < 4; q++) {
            int t = tid + q * 512;
            unsigned St = fhist[t], St1 = (t < 2047) ? fhist[t + 1] : 0u;
            if (St >= target && St1 < target) { sh_t = (unsigned)t; sh_above = St1; }
        }
        __syncthreads();
        unsigned t1 = sh_t; above += sh_above;
        __syncthreads();
        for (int t = tid; t < 2048; t += 512) fhist[t] = 0u;
        __syncthreads();
        unsigned pfx2 = (t0 << 11) | t1;
        for (int i = tid; i < NANCH; i += 512) {
            unsigned k = getkey(i);
            if ((k >> 10) == pfx2) atomicAdd(&fhist[k & 0x3FFu], 1u);
        }
        __syncthreads();
        suffix_scan_2048(fhist, tid);
        target = PREK - above;
#pragma unroll
        for (int q = 0; q < 4; q++) {
            int t = tid + q * 512;
            unsigned St = fhist[t], St1 = (t < 2047) ? fhist[t + 1] : 0u;
            if (St >= target && St1 < target) { sh_t = (unsigned)t; sh_above = St1; }
        }
        __syncthreads();
        unsigned t2 = sh_t; above += sh_above;
        unsigned B = (t0 << 21) | (t1 << 10) | t2;
        unsigned R = PREK - above;
        if (tid == 0) { s_cnt = 0u; s_eq = 0u; }
        __syncthreads();
        for (int i = tid; i < NANCH; i += 512) {
            unsigned k = getkey(i);
            if (k > B) {
                unsigned p = atomicAdd(&s_cnt, 1u);
                clist[p] = ((unsigned long long)k << 32) | (unsigned long long)(0xFFFFFFFFu - (unsigned)i);
            } else if (k == B) {
                unsigned p = atomicAdd(&s_eq, 1u);
                if (p < 1024u) eqlist[p] = (unsigned)i;
            }
        }
        __syncthreads();
        unsigned eqn = s_eq < 1024u ? s_eq : 1024u;
        for (int t = tid; t < 1024; t += 512)
            if ((unsigned)t >= eqn) eqlist[t] = 0xFFFFFFFFu;
        __syncthreads();
        for (unsigned k2 = 2; k2 <= 1024; k2 <<= 1)
            for (unsigned j = k2 >> 1; j > 0; j >>= 1) {
                for (int i = tid; i < 1024; i += 512) {
                    unsigned ixj = (unsigned)i ^ j;
                    if (ixj > (unsigned)i) {
                        unsigned a = eqlist[i], bb = eqlist[ixj];
                        bool asc = (((unsigned)i & k2) == 0u);
                        if (asc ? (a > bb) : (a < bb)) { eqlist[i] = bb; eqlist[ixj] = a; }
                    }
                }
                __syncthreads();
            }
        for (unsigned t = tid; t < R; t += 512) {
            unsigned idxe = eqlist[t];
            clist[above + t] = ((unsigned long long)B << 32) | (unsigned long long)(0xFFFFFFFFu - idxe);
        }
        __syncthreads();
        for (unsigned k2 = 2; k2 <= PREK; k2 <<= 1)
            for (unsigned j = k2 >> 1; j > 0; j >>= 1) {
                unsigned i = (unsigned)tid, ixj = i ^ j;
                if (ixj > i) {
                    unsigned long long a = clist[i], bb = clist[ixj];
                    bool desc = ((i & k2) == 0u);
                    if (desc ? (a < bb) : (a > bb)) { clist[i] = bb; clist[ixj] = a; }
                }
                __syncthreads();
            }
        __syncthreads();
    }

    // ---- decode candidate tid into REGISTERS (exact reference math) ----
    unsigned long long e = fastb ? sout[tid] : clist[tid];
    unsigned key = (unsigned)(e >> 32);
    unsigned aidx = 0xFFFFFFFFu - (unsigned)(e & 0xFFFFFFFFull);
    float score = mono_val(key);
    const float4 pv = *(const float4*)(pred + ((size_t)b * NANCH + aidx) * 84);
    float ax, ay, aw, ah;
    anchor_at((int)aidx, ax, ay, aw, ah);
    float bx = pv.x * 0.1f, by = pv.y * 0.1f, bw2 = pv.z * 0.2f, bh2 = pv.w * 0.2f;
    float cx = bx * aw + ax, cy = by * ah + ay;
    float w = (float)exp((double)bw2) * aw;
    float h = (float)exp((double)bh2) * ah;
    float x1 = cx - w * 0.5f, y1 = cy - h * 0.5f;
    float x2 = cx + w * 0.5f, y2 = cy + h * 0.5f;
    float area = (x2 - x1) * (y2 - y1);
    int validr = (score > CONF_THRF) ? 1 : 0;
    __syncthreads();             // all reads of clist/sout done -> overlay reusable

    // ---- NMS phase (overlayed LDS) ----
    sbox[tid] = make_float4(x1, y1, x2, y2);
    sarea[tid] = area;
    svalid[tid] = validr;
    for (int i = tid; i < 512 * 17; i += 512) rowb[i] = 0u;   // unbuilt cols read as 0
    int w_ = tid >> 6, lane6 = tid & 63;
    unsigned long long vbal = __ballot(validr != 0);
    if (lane6 == 0) {
        svalw[2 * w_] = (unsigned)vbal;
        svalw[2 * w_ + 1] = (unsigned)(vbal >> 32);
    }
    if (tid < 16) keepw[tid] = 0xFFFFFFFFu;
    if (tid == 0) s_kept = 0u;
    __syncthreads();

    for (int cc = 0; cc < 4; cc++) {
        int ntiles = 4 * cc + 3;
        for (int p = w_; p < ntiles; p += 8) {
            int fct = 2 * cc + 1;
            int ct = (p < fct) ? 2 * cc : 2 * cc + 1;
            int rt = (p < fct) ? p : p - fct;
            int r = rt * 64 + lane6;
            float4 br = sbox[r];
            float ar = sarea[r];
            int vr = svalid[r];
            unsigned m0 = 0u, m1 = 0u;
#pragma unroll 8
            for (int jj = 0; jj < 64; jj++) {
                int j = ct * 64 + jj;
                float4 bj = sbox[j];
                float aj = sarea[j];
                float xx1 = fmaxf(br.x, bj.x);
                float yy1 = fmaxf(br.y, bj.y);
                float xx2 = fminf(br.z, bj.z);
                float yy2 = fminf(br.w, bj.w);
                float ww = fmaxf(xx2 - xx1, 0.0f);
                float hh = fmaxf(yy2 - yy1, 0.0f);
                float inter = ww * hh;
                float uni = ar + aj - inter;
                float iou = inter / fmaxf(uni, 1e-8f);   // exact reference arithmetic
                bool sup = (iou > IOU_THRF) && (j > r) && vr;
                if (jj < 32) m0 |= sup ? (1u << jj) : 0u;
                else         m1 |= sup ? (1u << (jj - 32)) : 0u;
            }
            rowb[r * 17 + 2 * ct] = m0;
            rowb[r * 17 + 2 * ct + 1] = m1;
        }
        __syncthreads();

        if (tid < 64) {
            int w16 = tid & 15;
            unsigned kw = keepw[w16];
            if (cc > 0) {
                unsigned a0 = 0u, a1 = 0u, a2 = 0u, a3 = 0u;
                for (int i = tid; i < 128 * cc; i += 64) {
                    bool ki = (keepw[i >> 5] >> (i & 31)) & 1u;
                    if (ki) {
                        a0 |= rowb[i * 17 + 4 * cc + 0];
                        a1 |= rowb[i * 17 + 4 * cc + 1];
                        a2 |= rowb[i * 17 + 4 * cc + 2];
                        a3 |= rowb[i * 17 + 4 * cc + 3];
                    }
                }
#pragma unroll
                for (int d = 1; d < 64; d <<= 1) {
                    a0 |= (unsigned)__shfl_xor((int)a0, d, 64);
                    a1 |= (unsigned)__shfl_xor((int)a1, d, 64);
                    a2 |= (unsigned)__shfl_xor((int)a2, d, 64);
                    a3 |= (unsigned)__shfl_xor((int)a3, d, 64);
                }
                if (w16 == 4 * cc + 0) kw &= ~a0;
                if (w16 == 4 * cc + 1) kw &= ~a1;
                if (w16 == 4 * cc + 2) kw &= ~a2;
                if (w16 == 4 * cc + 3) kw &= ~a3;
            }
            for (int cch = 4 * cc; cch < 4 * cc + 4; cch++) {
                unsigned local = (unsigned)__shfl((int)kw, cch);
                for (int ii = 0; ii < 32; ii++) {
                    int i = cch * 32 + ii;
                    unsigned rb = rowb[i * 17 + w16];
                    unsigned rloc = rowb[i * 17 + cch];
                    if ((local >> ii) & 1u) {
                        local &= ~rloc;
                        kw &= ~rb;
                    }
                }
            }
            if (tid < 16) keepw[w16] = kw;
            unsigned cntv = (tid < 16 && w16 < 4 * (cc + 1))
                          ? (unsigned)__popc(kw & svalw[w16]) : 0u;
#pragma unroll
            for (int d = 1; d < 64; d <<= 1) cntv += (unsigned)__shfl_xor((int)cntv, d, 64);
            if (tid == 0) s_kept = cntv;
        }
        __syncthreads();
        if (s_kept >= MAXDET) break;
    }

    // ---- ballot compaction -> per-class top-100 ----
    unsigned kbit = (keepw[tid >> 5] >> (tid & 31)) & 1u;
    int kept = (int)kbit & validr;
    unsigned long long bal = __ballot(kept != 0);
    if (lane6 == 0) wsum[w_] = (unsigned)__popcll(bal);
    __syncthreads();
    int rank = 0;
    for (int u = 0; u < w_; u++) rank += (int)wsum[u];
    rank += (int)__popcll(bal & ((1ull << lane6) - 1ull));

    float* cs = cls_scores + (size_t)bc * MAXDET;
    float* cb = cls_boxes + (size_t)bc * MAXDET * 4;
    for (int r = tid; r < MAXDET; r += 512) {
        cs[r] = -1.0f;
        cb[r * 4 + 0] = -1.0f; cb[r * 4 + 1] = -1.0f;
        cb[r * 4 + 2] = -1.0f; cb[r * 4 + 3] = -1.0f;
    }
    __syncthreads();
    if (kept && rank < MAXDET) {
        cs[rank] = score;
        cb[rank * 4 + 0] = cx; cb[rank * 4 + 1] = cy;
        cb[rank * 4 + 2] = w;  cb[rank * 4 + 3] = h;
    }

    // ---- last-block-done epilogue: image-wide top-100 (512 thr x 16 keys) ----
    __threadfence();
    __syncthreads();
    if (tid == 0) {
        unsigned prev = atomicAdd(&done[b], 1u);
        s_last = (prev == NCLS - 1) ? 1 : 0;
    }
    __syncthreads();
    if (!s_last) return;
    __threadfence();

    unsigned idx0 = (unsigned)tid * 16u;
    unsigned rk[16];
#pragma unroll
    for (int e2 = 0; e2 < 16; e2++) {
        unsigned i = idx0 + (unsigned)e2;
        rk[e2] = (i < (unsigned)(NCLS * MAXDET))
               ? mono_key(cls_scores[(size_t)b * NCLS * MAXDET + i]) : 0u;
    }
    if (tid == 0) { s_prefix = 0u; s_need = MAXDET; }
    __syncthreads();

    for (int pass = 0; pass < 4; pass++) {
        int shift = 24 - 8 * pass;
        if (tid < 256) thist[tid] = 0u;
        __syncthreads();
        unsigned pfx = s_prefix;
#pragma unroll
        for (int e2 = 0; e2 < 16; e2++) {
            unsigned k = rk[e2];
            if (pass == 0 || (k >> (shift + 8)) == pfx)
                atomicAdd(&thist[(k >> shift) & 0xFFu], 1u);
        }
        __syncthreads();
        unsigned v = 0u;
        if (tid < 256) {
            v = thist[tid];
            int lane = tid & 63;
#pragma unroll
            for (int off = 1; off < 64; off <<= 1) {
                unsigned u = (unsigned)__shfl_down((int)v, off, 64);
                if (lane + off < 64) v += u;
            }
            if (lane == 0) wpart[tid >> 6] = v;
        }
        __syncthreads();
        if (tid == 0) {
            unsigned acc = 0;
            for (int ww = 3; ww >= 0; ww--) { unsigned t = wpart[ww]; wpart[ww] = acc; acc += t; }
        }
        __syncthreads();
        if (tid < 256) { v += wpart[tid >> 6]; thist[tid] = v; }
        __syncthreads();
        unsigned nd = s_need;
        if (tid < 256) {
            unsigned S = thist[tid], S1 = (tid < 255) ? thist[tid + 1] : 0u;
            if (S >= nd && S1 < nd) { s_bin = (unsigned)tid; s_abv = S1; }
        }
        __syncthreads();
        if (tid == 0) { s_prefix = (s_prefix << 8) | s_bin; s_need = s_need - s_abv; }
        __syncthreads();
    }
    unsigned K = s_prefix;       // exact 100th-largest key
    unsigned R = s_need;         // key==K entries to take by flat index asc, >=1

    if (tid < 256) thist[tid] = 0u;
    __syncthreads();
#pragma unroll
    for (int e2 = 0; e2 < 16; e2++) {
        unsigned i = idx0 + (unsigned)e2;
        if (rk[e2] == K) atomicAdd(&thist[i >> 5], 1u);    // 256 bins of 32 indices
    }
    __syncthreads();
    unsigned v2 = 0u;
    if (tid < 256) {
        v2 = thist[tid];
        int lane = tid & 63;
#pragma unroll
        for (int off = 1; off < 64; off <<= 1) {
            unsigned u = (unsigned)__shfl_up((int)v2, off, 64);
            if (lane >= off) v2 += u;
        }
        if (lane == 63) wpart[tid >> 6] = v2;
    }
    __syncthreads();
    if (tid == 0) {
        unsigned acc = 0;
        for (int ww = 0; ww < 4; ww++) { unsigned t = wpart[ww]; wpart[ww] = acc; acc += t; }
    }
    __syncthreads();
    if (tid < 256) { v2 += wpart[tid >> 6]; thist[tid] = v2; }
    __syncthreads();
    if (tid < 256) {
        unsigned C = thist[tid], C0 = (tid > 0) ? thist[tid - 1] : 0u;
        if (C >= R && C0 < R) { s_bin = (unsigned)tid; s_abv = R - C0; }
    }
    __syncthreads();
    unsigned tA = s_bin, Rrem = s_abv;
    if (tid < 32) thist[tid] = 0u;
    __syncthreads();
#pragma unroll
    for (int e2 = 0; e2 < 16; e2++) {
        unsigned i = idx0 + (unsigned)e2;
        if (rk[e2] == K && (i >> 5) == tA) atomicAdd(&thist[i & 31u], 1u);
    }
    __syncthreads();
    if (tid < 32) {
        unsigned vv = thist[tid];
        unsigned own = vv;
#pragma unroll
        for (int off = 1; off < 32; off <<= 1) {
            unsigned u = (unsigned)__shfl_up((int)vv, off, 64);
            if (tid >= off) vv += u;
        }
        unsigned C0 = vv - own;
        if (vv >= Rrem && C0 < Rrem) s_istar = (tA << 5) | (unsigned)tid;
    }
    if (tid == 0) w_ctr = 0u;
    __syncthreads();
    unsigned Istar = s_istar;

#pragma unroll
    for (int e2 = 0; e2 < 16; e2++) {
        unsigned i = idx0 + (unsigned)e2;
        unsigned k = rk[e2];
        if (k > K || (k == K && i <= Istar)) {
            unsigned p = atomicAdd(&w_ctr, 1u);
            if (p < 128u)
                win[p] = ((unsigned long long)k << 32)
                       | (unsigned long long)(0xFFFFFFFFu - i);
        }
    }
    __syncthreads();
    if (tid >= (int)w_ctr && tid < 128) win[tid] = 0ull;
    __syncthreads();

    if (tid < 64) {
        unsigned i0 = (unsigned)tid * 2u, i1 = i0 + 1u;
        unsigned long long v0 = win[i0], v1 = win[i1];
        for (unsigned k2 = 2; k2 <= 128; k2 <<= 1) {
            for (unsigned j = k2 >> 1; j >= 1; j >>= 1) {
                if (j >= 2) {
                    int d = (int)(j >> 1);
                    unsigned long long u0 = shflx64(v0, d), u1 = shflx64(v1, d);
                    v0 = ce_dir(v0, u0, i0, j, k2);
                    v1 = ce_dir(v1, u1, i1, j, k2);
                } else {
                    bool tm = ((i0 & k2) == 0u);
                    unsigned long long mx = v0 > v1 ? v0 : v1;
                    unsigned long long mn = v0 > v1 ? v1 : v0;
                    v0 = tm ? mx : mn; v1 = tm ? mn : mx;
                }
            }
        }
        win[i0] = v0; win[i1] = v1;
    }
    __syncthreads();

    bool vd = false;
    if (tid < MAXDET) {
        unsigned long long e3 = win[tid];
        unsigned mk = (unsigned)(e3 >> 32);
        float s = mono_val(mk);
        unsigned fi = 0xFFFFFFFFu - (unsigned)(e3 & 0xFFFFFFFFull);
        vd = (s >= CONF_THRF);
        float obx = -1.0f, oby = -1.0f, obw = -1.0f, obh = -1.0f;
        float ofs = -1.0f, ofc = -1.0f;
        if (vd) {
            const float* bp = cls_boxes + ((size_t)b * NCLS * MAXDET + fi) * 4;
            obx = bp[0]; oby = bp[1]; obw = bp[2]; obh = bp[3];
            ofs = s;
            ofc = (float)(fi / MAXDET);
        }
        int o = b * MAXDET + tid;
        out[o * 4 + 0] = obx; out[o * 4 + 1] = oby;
        out[o * 4 + 2] = obw; out[o * 4 + 3] = obh;
        out[NIMG * MAXDET * 4 + o] = ofs;
        out[NIMG * MAXDET * 5 + o] = ofc;
    }
    unsigned long long bal2 = __ballot(vd);
    if ((tid & 63) == 0) balw[tid >> 6] = bal2;
    __syncthreads();
    if (tid == 0) {
        int cnt2 = 0;
        for (int u = 0; u < 8; u++) cnt2 += (int)__popcll(balw[u]);
        out[NIMG * MAXDET * 6 + b] = (float)cnt2;
    }
}

extern "C" void kernel_launch(void* const* d_in, const int* in_sizes, int n_in,
                              void* d_out, int out_size, void* d_ws, size_t ws_size,
                              hipStream_t stream) {
    (void)in_sizes; (void)n_in; (void)out_size; (void)ws_size;
    const float* pred = (const float*)d_in[1];  // d_in[0] = images (only H=W=640 used)
    float* out = (float*)d_out;

    char* base = (char*)d_ws;
    size_t off = 0;
    unsigned* gcnt = (unsigned*)(base + off);                  // 5120 x 64B = 327,680
    off += (size_t)NSUB * 16 * sizeof(unsigned);
    unsigned* done = (unsigned*)(base + off);                  // 4 counters (+pad to 64B)
    off += 64;
    unsigned long long* glist = (unsigned long long*)(base + off);  // 5.24 MB
    off += (size_t)NSUB * SCAP * 8u;
    float* cls_scores = (float*)(base + off);                  // 128 KB
    off += (size_t)NBC * MAXDET * sizeof(float);
    float* cls_boxes = (float*)(base + off);                   // 512 KB

    // one memset covers gcnt + done
    hipMemsetAsync(gcnt, 0, (size_t)NSUB * 16 * sizeof(unsigned) + 64, stream);
    collect_kernel<<<dim3(630, NIMG), 256, 0, stream>>>(pred, glist, gcnt);
    select_nms_fused<<<NBC, 512, 0, stream>>>(pred, glist, gcnt,
                                              cls_scores, cls_boxes, done, out);
}